// Round 9
// baseline (1680.781 us; speedup 1.0000x reference)
//
#include <hip/hip_runtime.h>
#include <math.h>

#define BS   2048
#define SEQ  50
#define NPOS (BS * SEQ)

__device__ __forceinline__ float sigf(float x) { return 1.0f / (1.0f + __expf(-x)); }
__device__ __forceinline__ float tanhfast(float x) {
    float e = __expf(2.0f * x);
    return 1.0f - 2.0f / (e + 1.0f);
}

// ---- macro toolkit: named-SSA values only (NO private arrays) -------------
#define FMA4(A, X, W) \
    A = fmaf((X).x, (W).x, A); A = fmaf((X).y, (W).y, A); \
    A = fmaf((X).z, (W).z, A); A = fmaf((X).w, (W).w, A);

#define LD16(P, N) \
    float4 N##0=(P)[0],  N##1=(P)[1],  N##2=(P)[2],  N##3=(P)[3], \
           N##4=(P)[4],  N##5=(P)[5],  N##6=(P)[6],  N##7=(P)[7], \
           N##8=(P)[8],  N##9=(P)[9],  N##10=(P)[10],N##11=(P)[11], \
           N##12=(P)[12],N##13=(P)[13],N##14=(P)[14],N##15=(P)[15];

#define LD4(P, N) \
    float4 N##0=(P)[0], N##1=(P)[1], N##2=(P)[2], N##3=(P)[3];

// ---------------------------------------------------------------------------
// Kernel A: unchanged from R6/R8 (~300 us; lstm is the target this round).
// ---------------------------------------------------------------------------
__global__
__attribute__((amdgpu_flat_work_group_size(64, 64), amdgpu_waves_per_eu(2, 2)))
void edge_attn_ctx(
    const float* __restrict__ seqs,   // [BS,SEQ,3,3,6]
    const float* __restrict__ ets,    // [BS,SEQ,3,3,4]
    const int*   __restrict__ masks,  // [BS,SEQ,3,3]
    const float* __restrict__ Wf, const float* __restrict__ bf,
    const float* __restrict__ Wk, const float* __restrict__ bk,
    const float* __restrict__ Wq, const float* __restrict__ bq,
    const float* __restrict__ Wv, const float* __restrict__ bv,
    float* __restrict__ ctx)          // [BS,SEQ,64]
{
    const int o = threadIdx.x;

    const float4* qp = (const float4*)&Wq[o * 64];
    LD16(qp, wq)
    const float4* vp = (const float4*)&Wv[o * 64];
    LD16(vp, wv)

    const float* wfp = &Wf[o * 19];
    float wf0=wfp[0], wf1=wfp[1], wf2=wfp[2], wf3=wfp[3], wf4=wfp[4], wf5=wfp[5],
          wf6=wfp[6], wf7=wfp[7], wf8=wfp[8], wf9=wfp[9];
    float wfe0=wfp[10], wfe1=wfp[11], wfe2=wfp[12], wfe3=wfp[13], wfe4=wfp[14],
          wfe5=wfp[15], wfe6=wfp[16], wfe7=wfp[17], wfe8=wfp[18];
    const float* wkp = &Wk[o * 6];
    float wk0=wkp[0], wk1=wkp[1], wk2=wkp[2], wk3=wkp[3], wk4=wkp[4], wk5=wkp[5];

    const float bfr = bf[o], bkr = bk[o], bqr = bq[o], bvr = bv[o];

    __shared__ float s_seq[54];
    __shared__ float s_et[36];
    __shared__ int   s_mask[9];
    __shared__ float s_edge[9 * 64];

    for (int p = blockIdx.x; p < NPOS; p += gridDim.x) {
        if (o < 54) s_seq[o]  = seqs[p * 54 + o];
        if (o < 36) s_et[o]   = ets[p * 36 + o];
        if (o < 9)  s_mask[o] = masks[p * 9 + o];
        __syncthreads();

        float wfe[9] = {wfe0,wfe1,wfe2,wfe3,wfe4,wfe5,wfe6,wfe7,wfe8};
        #pragma unroll
        for (int e = 0; e < 9; ++e) {
            float v = bfr + wfe[e];
            v = fmaf(s_seq[e*6+0], wf0, v);
            v = fmaf(s_seq[e*6+1], wf1, v);
            v = fmaf(s_seq[e*6+2], wf2, v);
            v = fmaf(s_seq[e*6+3], wf3, v);
            v = fmaf(s_seq[e*6+4], wf4, v);
            v = fmaf(s_seq[e*6+5], wf5, v);
            v = fmaf(s_et[e*4+0],  wf6, v);
            v = fmaf(s_et[e*4+1],  wf7, v);
            v = fmaf(s_et[e*4+2],  wf8, v);
            v = fmaf(s_et[e*4+3],  wf9, v);
            s_edge[e * 64 + o] = v;
        }
        float key = bkr;
        key = fmaf(s_seq[24], wk0, key);
        key = fmaf(s_seq[25], wk1, key);
        key = fmaf(s_seq[26], wk2, key);
        key = fmaf(s_seq[27], wk3, key);
        key = fmaf(s_seq[28], wk4, key);
        key = fmaf(s_seq[29], wk5, key);
        __syncthreads();

        float vv[9], att[9];
        #pragma unroll
        for (int e = 0; e < 9; ++e) {
            const float4* ep = (const float4*)&s_edge[e * 64];
            float q = 0.f, v = 0.f;
            {
                float4 t;
                t=ep[0];  FMA4(q,t,wq0)  FMA4(v,t,wv0)
                t=ep[1];  FMA4(q,t,wq1)  FMA4(v,t,wv1)
                t=ep[2];  FMA4(q,t,wq2)  FMA4(v,t,wv2)
                t=ep[3];  FMA4(q,t,wq3)  FMA4(v,t,wv3)
                t=ep[4];  FMA4(q,t,wq4)  FMA4(v,t,wv4)
                t=ep[5];  FMA4(q,t,wq5)  FMA4(v,t,wv5)
                t=ep[6];  FMA4(q,t,wq6)  FMA4(v,t,wv6)
                t=ep[7];  FMA4(q,t,wq7)  FMA4(v,t,wv7)
                t=ep[8];  FMA4(q,t,wq8)  FMA4(v,t,wv8)
                t=ep[9];  FMA4(q,t,wq9)  FMA4(v,t,wv9)
                t=ep[10]; FMA4(q,t,wq10) FMA4(v,t,wv10)
                t=ep[11]; FMA4(q,t,wq11) FMA4(v,t,wv11)
                t=ep[12]; FMA4(q,t,wq12) FMA4(v,t,wv12)
                t=ep[13]; FMA4(q,t,wq13) FMA4(v,t,wv13)
                t=ep[14]; FMA4(q,t,wq14) FMA4(v,t,wv14)
                t=ep[15]; FMA4(q,t,wq15) FMA4(v,t,wv15)
            }
            float qq = bqr + q;
            vv[e] = bvr + v;
            float a_ = key * qq;
            a_ += __shfl_xor(a_, 8, 16);
            a_ += __shfl_xor(a_, 4, 16);
            a_ += __shfl_xor(a_, 2, 16);
            a_ += __shfl_xor(a_, 1, 16);
            att[e] = a_ * 0.25f;   // / sqrt(16)
        }

        float mx = -3.0e38f;
        #pragma unroll
        for (int e = 0; e < 9; ++e) {
            att[e] = (s_mask[e] == 0) ? -1.0e10f : att[e];
            mx = fmaxf(mx, att[e]);
        }
        float ssum = 0.f;
        #pragma unroll
        for (int e = 0; e < 9; ++e) { att[e] = __expf(att[e] - mx); ssum += att[e]; }
        float inv = 1.f / ssum;
        float acc = 0.f;
        #pragma unroll
        for (int e = 0; e < 9; ++e) acc = fmaf(att[e], vv[e], acc);
        ctx[p * 64 + o] = acc * inv;
        __syncthreads();
    }
}

// ---------------------------------------------------------------------------
// Kernel C v7: T_g=4 gates x 4-way k-split, 4 rows/block, 512 blocks x 512thr
// (2 blocks/CU). Halves the LDS-read wall vs R8 (48 b128/thread/step, 16 FMA
// per read). wi resident (16 f4 = 64 VGPR); W_hh streamed in-loop DIRECT from
// d_in (L2-resident, R6/R8-proven; no ws transpose -> no LICM spill).
// Skews: x-quarters +20 dwords (banks 0/20/8/28), h-quarters +36 (0/4/8/12):
// the 4 concurrent read addresses land on disjoint bank quads.
// ---------------------------------------------------------------------------
#define XROW 80    // floats per s_x row (quarters of 16 at cols 0/20/40/60)
#define HROW 144   // floats per s_h row (quarters of 32 at cols 0/36/72/108)
#define SGS  516   // s_g row stride (floats); 516*4B = 2064 B, 16B-aligned

#define XR(kk, r) { float4 x_ = sx4[(r)*20 + kq5 + (kk)]; \
    FMA4(A0##r,x_,wi0##kk) FMA4(A1##r,x_,wi1##kk) \
    FMA4(A2##r,x_,wi2##kk) FMA4(A3##r,x_,wi3##kk) }
#define XK(kk) XR(kk,0) XR(kk,1) XR(kk,2) XR(kk,3)

#define HR(kk, r) { float4 h_ = sh4[(r)*36 + kq9 + (kk)]; \
    FMA4(A0##r,h_,w0_) FMA4(A1##r,h_,w1_) FMA4(A2##r,h_,w2_) FMA4(A3##r,h_,w3_) }
#define HK(kk) { \
    float4 w0_=whp0[kk], w1_=whp1[kk], w2_=whp2[kk], w3_=whp3[kk]; \
    HR(kk,0) HR(kk,1) HR(kk,2) HR(kk,3) }

#define RED2(A) A += __shfl_xor(A, 1); A += __shfl_xor(A, 2);
#define SELR(g) (kq == 0 ? A##g##0 : kq == 1 ? A##g##1 : kq == 2 ? A##g##2 : A##g##3)

__global__ __launch_bounds__(512)
void lstm_out(
    const float* __restrict__ ctx,    // [BS,SEQ,64]
    const float* __restrict__ W_ih,   // [512,64]
    const float* __restrict__ W_hh,   // [512,128]
    const float* __restrict__ b_ih, const float* __restrict__ b_hh,
    const float* __restrict__ W_out,  // [64,128]
    const float* __restrict__ b_out,  // [64]
    float* __restrict__ out)          // [BS,64]
{
    const int t    = threadIdx.x;
    const int gq   = t >> 2;          // gate quad 0..127 -> gates 4gq..4gq+3
    const int kq   = t & 3;           // k-quarter
    const int kq5  = kq * 5;          // x quarter offset (float4s)
    const int kq9  = kq * 9;          // h quarter offset (float4s)
    const int jb   = gq * 4;
    const int row0 = blockIdx.x * 4;
    const int pr   = t >> 7;          // pointwise row 0..3
    const int pm   = t & 127;         // pointwise elem 0..127

    // resident W_ih quarter-rows for 4 gates: 16 float4 = 64 VGPR
    const float4* p0 = (const float4*)&W_ih[(jb + 0) * 64 + kq * 16];
    LD4(p0, wi0)
    const float4* p1 = (const float4*)&W_ih[(jb + 1) * 64 + kq * 16];
    LD4(p1, wi1)
    const float4* p2 = (const float4*)&W_ih[(jb + 2) * 64 + kq * 16];
    LD4(p2, wi2)
    const float4* p3 = (const float4*)&W_ih[(jb + 3) * 64 + kq * 16];
    LD4(p3, wi3)

    // W_hh stream bases (direct from d_in: scattered but L2-resident)
    const float4* whp0 = (const float4*)&W_hh[(jb + 0) * 128 + kq * 32];
    const float4* whp1 = (const float4*)&W_hh[(jb + 1) * 128 + kq * 32];
    const float4* whp2 = (const float4*)&W_hh[(jb + 2) * 128 + kq * 32];
    const float4* whp3 = (const float4*)&W_hh[(jb + 3) * 128 + kq * 32];

    // pointwise biases (gate order i,f,g,o = rows 0/128/256/384)
    const float bi = b_ih[pm]       + b_hh[pm];
    const float bF = b_ih[128 + pm] + b_hh[128 + pm];
    const float bg = b_ih[256 + pm] + b_hh[256 + pm];
    const float bo = b_ih[384 + pm] + b_hh[384 + pm];

    __shared__ float s_x[4 * XROW];
    __shared__ float s_h[4 * HROW];
    __shared__ float s_g[4 * SGS];

    const float4* sx4 = (const float4*)s_x;
    const float4* sh4 = (const float4*)s_h;

    const int hcol = (pm >> 5) * 36 + (pm & 31);   // pointwise h write col

    float c = 0.f;

    for (int s = 0; s < SEQ; ++s) {
        if (t < 256) {                 // stage x for this step (waves 0-3)
            const int sr = t >> 6, sm = t & 63;
            s_x[sr * XROW + (sm >> 4) * 20 + (sm & 15)] =
                ctx[((row0 + sr) * SEQ + s) * 64 + sm];
        }
        __syncthreads();

        float A00=0.f,A01=0.f,A02=0.f,A03=0.f;
        float A10=0.f,A11=0.f,A12=0.f,A13=0.f;
        float A20=0.f,A21=0.f,A22=0.f,A23=0.f;
        float A30=0.f,A31=0.f,A32=0.f,A33=0.f;

        XK(0) XK(1) XK(2) XK(3)
        if (s > 0) {
            HK(0) HK(1) HK(2) HK(3) HK(4) HK(5) HK(6) HK(7)
        }

        RED2(A00) RED2(A01) RED2(A02) RED2(A03)
        RED2(A10) RED2(A11) RED2(A12) RED2(A13)
        RED2(A20) RED2(A21) RED2(A22) RED2(A23)
        RED2(A30) RED2(A31) RED2(A32) RED2(A33)

        {   // lane kq writes row kq, gates 4gq..4gq+3 (one b128)
            float4 gv = make_float4(SELR(0), SELR(1), SELR(2), SELR(3));
            *(float4*)&s_g[kq * SGS + (gq << 2)] = gv;
        }
        __syncthreads();

        {   // pointwise: thread (pr, pm); c-state in register
            const float* g0 = &s_g[pr * SGS];
            float ig = sigf(g0[pm] + bi);
            float fg = sigf(g0[128 + pm] + bF);
            float gt = tanhfast(g0[256 + pm] + bg);
            float og = sigf(g0[384 + pm] + bo);
            c = fmaf(fg, c, ig * gt);
            s_h[pr * HROW + hcol] = og * tanhfast(c);
        }
        __syncthreads();
    }

    // epilogue: out[row0+r][o] = b_out[o] + h[r] . W_out[o]
    if (t < 256) {
        const int r = t >> 6, o = t & 63;
        float acc = b_out[o];
        const float4* wp = (const float4*)&W_out[o * 128];
        #pragma unroll
        for (int q = 0; q < 4; ++q)
            #pragma unroll
            for (int i = 0; i < 8; ++i) {
                float4 h4 = sh4[r * 36 + q * 9 + i];   // broadcast read
                float4 w4 = wp[q * 8 + i];
                FMA4(acc, h4, w4)
            }
        out[(row0 + r) * 64 + o] = acc;
    }
}

// ---------------------------------------------------------------------------
extern "C" void kernel_launch(void* const* d_in, const int* in_sizes, int n_in,
                              void* d_out, int out_size, void* d_ws, size_t ws_size,
                              hipStream_t stream) {
    (void)in_sizes; (void)n_in; (void)out_size; (void)ws_size;
    const float* seqs  = (const float*)d_in[0];
    const float* ets   = (const float*)d_in[1];
    const int*   masks = (const int*)d_in[2];
    const float* Wf  = (const float*)d_in[3];
    const float* bf  = (const float*)d_in[4];
    const float* Wk  = (const float*)d_in[5];
    const float* bk  = (const float*)d_in[6];
    const float* Wq  = (const float*)d_in[7];
    const float* bq  = (const float*)d_in[8];
    const float* Wv  = (const float*)d_in[9];
    const float* bv  = (const float*)d_in[10];
    const float* Wih = (const float*)d_in[11];
    const float* Whh = (const float*)d_in[12];
    const float* bih = (const float*)d_in[13];
    const float* bhh = (const float*)d_in[14];
    const float* Wo  = (const float*)d_in[15];
    const float* bo  = (const float*)d_in[16];

    float* ctx = (float*)d_ws;  // [BS,SEQ,64] fp32 = 26.2 MB

    hipLaunchKernelGGL(edge_attn_ctx, dim3(4096), dim3(64), 0, stream,
                       seqs, ets, masks, Wf, bf, Wk, bk, Wq, bq, Wv, bv, ctx);
    hipLaunchKernelGGL(lstm_out, dim3(512), dim3(512), 0, stream,
                       ctx, Wih, Whh, bih, bhh, Wo, bo, (float*)d_out);
}

// Round 10
// 806.018 us; speedup vs baseline: 2.0853x; 2.0853x over previous
//
#include <hip/hip_runtime.h>
#include <math.h>

#define BS   2048
#define SEQ  50
#define NPOS (BS * SEQ)

__device__ __forceinline__ float sigf(float x) { return 1.0f / (1.0f + __expf(-x)); }
__device__ __forceinline__ float tanhfast(float x) {
    float e = __expf(2.0f * x);
    return 1.0f - 2.0f / (e + 1.0f);
}

// ---- macro toolkit: named-SSA values only (NO private arrays) -------------
#define FMA4(A, X, W) \
    A = fmaf((X).x, (W).x, A); A = fmaf((X).y, (W).y, A); \
    A = fmaf((X).z, (W).z, A); A = fmaf((X).w, (W).w, A);

#define LD16(P, N) \
    float4 N##0=(P)[0],  N##1=(P)[1],  N##2=(P)[2],  N##3=(P)[3], \
           N##4=(P)[4],  N##5=(P)[5],  N##6=(P)[6],  N##7=(P)[7], \
           N##8=(P)[8],  N##9=(P)[9],  N##10=(P)[10],N##11=(P)[11], \
           N##12=(P)[12],N##13=(P)[13],N##14=(P)[14],N##15=(P)[15];

// ---------------------------------------------------------------------------
// prep_w: transpose W_ih/W_hh into wave-contiguous layouts so the lstm's
// in-loop weight loads are perfectly coalesced (64 lanes x 16B contiguous).
//   wiT[(g*4+kk)*512 + t] = W_ih[(4*(t>>2)+g)*64  + (t&3)*16 + kk*4 ..+3]
//   whT[(g*8+kk)*512 + t] = W_hh[(4*(t>>2)+g)*128 + (t&3)*32 + kk*4 ..+3]
// 48 blocks: b<16 -> wiT chunk b; b>=16 -> whT chunk b-16.
// ---------------------------------------------------------------------------
__global__ __launch_bounds__(512) void prep_w(
    const float* __restrict__ Wih, const float* __restrict__ Whh,
    float4* __restrict__ wiT, float4* __restrict__ whT)
{
    const int t = threadIdx.x;
    const int gq = t >> 2, kq = t & 3;
    const int b = blockIdx.x;
    if (b < 16) {
        const int g = b >> 2, kk = b & 3;
        wiT[b * 512 + t] = *(const float4*)&Wih[(4*gq + g) * 64 + kq * 16 + kk * 4];
    } else {
        const int c = b - 16;
        const int g = c >> 3, kk = c & 7;
        whT[c * 512 + t] = *(const float4*)&Whh[(4*gq + g) * 128 + kq * 32 + kk * 4];
    }
}

// ---------------------------------------------------------------------------
// Kernel A: unchanged from R6/R8 (~320 us; lstm is the target this round).
// ---------------------------------------------------------------------------
__global__
__attribute__((amdgpu_flat_work_group_size(64, 64), amdgpu_waves_per_eu(2, 2)))
void edge_attn_ctx(
    const float* __restrict__ seqs,   // [BS,SEQ,3,3,6]
    const float* __restrict__ ets,    // [BS,SEQ,3,3,4]
    const int*   __restrict__ masks,  // [BS,SEQ,3,3]
    const float* __restrict__ Wf, const float* __restrict__ bf,
    const float* __restrict__ Wk, const float* __restrict__ bk,
    const float* __restrict__ Wq, const float* __restrict__ bq,
    const float* __restrict__ Wv, const float* __restrict__ bv,
    float* __restrict__ ctx)          // [BS,SEQ,64]
{
    const int o = threadIdx.x;

    const float4* qp = (const float4*)&Wq[o * 64];
    LD16(qp, wq)
    const float4* vp = (const float4*)&Wv[o * 64];
    LD16(vp, wv)

    const float* wfp = &Wf[o * 19];
    float wf0=wfp[0], wf1=wfp[1], wf2=wfp[2], wf3=wfp[3], wf4=wfp[4], wf5=wfp[5],
          wf6=wfp[6], wf7=wfp[7], wf8=wfp[8], wf9=wfp[9];
    float wfe0=wfp[10], wfe1=wfp[11], wfe2=wfp[12], wfe3=wfp[13], wfe4=wfp[14],
          wfe5=wfp[15], wfe6=wfp[16], wfe7=wfp[17], wfe8=wfp[18];
    const float* wkp = &Wk[o * 6];
    float wk0=wkp[0], wk1=wkp[1], wk2=wkp[2], wk3=wkp[3], wk4=wkp[4], wk5=wkp[5];

    const float bfr = bf[o], bkr = bk[o], bqr = bq[o], bvr = bv[o];

    __shared__ float s_seq[54];
    __shared__ float s_et[36];
    __shared__ int   s_mask[9];
    __shared__ float s_edge[9 * 64];

    for (int p = blockIdx.x; p < NPOS; p += gridDim.x) {
        if (o < 54) s_seq[o]  = seqs[p * 54 + o];
        if (o < 36) s_et[o]   = ets[p * 36 + o];
        if (o < 9)  s_mask[o] = masks[p * 9 + o];
        __syncthreads();

        float wfe[9] = {wfe0,wfe1,wfe2,wfe3,wfe4,wfe5,wfe6,wfe7,wfe8};
        #pragma unroll
        for (int e = 0; e < 9; ++e) {
            float v = bfr + wfe[e];
            v = fmaf(s_seq[e*6+0], wf0, v);
            v = fmaf(s_seq[e*6+1], wf1, v);
            v = fmaf(s_seq[e*6+2], wf2, v);
            v = fmaf(s_seq[e*6+3], wf3, v);
            v = fmaf(s_seq[e*6+4], wf4, v);
            v = fmaf(s_seq[e*6+5], wf5, v);
            v = fmaf(s_et[e*4+0],  wf6, v);
            v = fmaf(s_et[e*4+1],  wf7, v);
            v = fmaf(s_et[e*4+2],  wf8, v);
            v = fmaf(s_et[e*4+3],  wf9, v);
            s_edge[e * 64 + o] = v;
        }
        float key = bkr;
        key = fmaf(s_seq[24], wk0, key);
        key = fmaf(s_seq[25], wk1, key);
        key = fmaf(s_seq[26], wk2, key);
        key = fmaf(s_seq[27], wk3, key);
        key = fmaf(s_seq[28], wk4, key);
        key = fmaf(s_seq[29], wk5, key);
        __syncthreads();

        float vv[9], att[9];
        #pragma unroll
        for (int e = 0; e < 9; ++e) {
            const float4* ep = (const float4*)&s_edge[e * 64];
            float q = 0.f, v = 0.f;
            {
                float4 t;
                t=ep[0];  FMA4(q,t,wq0)  FMA4(v,t,wv0)
                t=ep[1];  FMA4(q,t,wq1)  FMA4(v,t,wv1)
                t=ep[2];  FMA4(q,t,wq2)  FMA4(v,t,wv2)
                t=ep[3];  FMA4(q,t,wq3)  FMA4(v,t,wv3)
                t=ep[4];  FMA4(q,t,wq4)  FMA4(v,t,wv4)
                t=ep[5];  FMA4(q,t,wq5)  FMA4(v,t,wv5)
                t=ep[6];  FMA4(q,t,wq6)  FMA4(v,t,wv6)
                t=ep[7];  FMA4(q,t,wq7)  FMA4(v,t,wv7)
                t=ep[8];  FMA4(q,t,wq8)  FMA4(v,t,wv8)
                t=ep[9];  FMA4(q,t,wq9)  FMA4(v,t,wv9)
                t=ep[10]; FMA4(q,t,wq10) FMA4(v,t,wv10)
                t=ep[11]; FMA4(q,t,wq11) FMA4(v,t,wv11)
                t=ep[12]; FMA4(q,t,wq12) FMA4(v,t,wv12)
                t=ep[13]; FMA4(q,t,wq13) FMA4(v,t,wv13)
                t=ep[14]; FMA4(q,t,wq14) FMA4(v,t,wv14)
                t=ep[15]; FMA4(q,t,wq15) FMA4(v,t,wv15)
            }
            float qq = bqr + q;
            vv[e] = bvr + v;
            float a_ = key * qq;
            a_ += __shfl_xor(a_, 8, 16);
            a_ += __shfl_xor(a_, 4, 16);
            a_ += __shfl_xor(a_, 2, 16);
            a_ += __shfl_xor(a_, 1, 16);
            att[e] = a_ * 0.25f;   // / sqrt(16)
        }

        float mx = -3.0e38f;
        #pragma unroll
        for (int e = 0; e < 9; ++e) {
            att[e] = (s_mask[e] == 0) ? -1.0e10f : att[e];
            mx = fmaxf(mx, att[e]);
        }
        float ssum = 0.f;
        #pragma unroll
        for (int e = 0; e < 9; ++e) { att[e] = __expf(att[e] - mx); ssum += att[e]; }
        float inv = 1.f / ssum;
        float acc = 0.f;
        #pragma unroll
        for (int e = 0; e < 9; ++e) acc = fmaf(att[e], vv[e], acc);
        ctx[p * 64 + o] = acc * inv;
        __syncthreads();
    }
}

// ---------------------------------------------------------------------------
// Kernel C v8: G=4 gates x S=4 k-split, R=8 rows, 256 blocks x 512 thr.
//  - LDS reads 96/thread/step (half of R8) -> LDS wall ~193 us.
//  - Weights streamed in-loop from TRANSPOSED wiT/whT: each wave-load is 64
//    contiguous 16B lanes (no line inflation; R6/R8 scattered ~4x).
//  - LICM defeat: chunk index rotated by s (kk' = (kk+s)&mask) so weight
//    addresses depend on the loop var (R7 hoist->spill cannot recur).
//    Activation chunk uses the same kk' -> sum is permutation-invariant.
//  - acc 32 + temps ~ 70 VGPR: far under the 128 budget.
//  Skews: x quarters at +20 floats, h quarters at +36 -> 4 concurrent LDS
//  addresses on disjoint bank quads (R9 measured conflicts ~0).
// ---------------------------------------------------------------------------
#define XROW 80    // floats per s_x row (quarters of 16 at cols 0/20/40/60)
#define HROWF 144  // floats per s_h row (quarters of 32 at cols 0/36/72/108)
#define SGS  516   // s_g row stride (floats)

#define XG(kk) { \
    const int kk2 = ((kk) + s) & 3; \
    const int wb = kk2 * 512 + t; \
    float4 w0_ = wiT[0*2048 + wb]; \
    float4 w1_ = wiT[1*2048 + wb]; \
    float4 w2_ = wiT[2*2048 + wb]; \
    float4 w3_ = wiT[3*2048 + wb]; \
    float4 x_; \
    x_ = sx4[0*20 + kq5 + kk2]; FMA4(A00,x_,w0_) FMA4(A10,x_,w1_) FMA4(A20,x_,w2_) FMA4(A30,x_,w3_) \
    x_ = sx4[1*20 + kq5 + kk2]; FMA4(A01,x_,w0_) FMA4(A11,x_,w1_) FMA4(A21,x_,w2_) FMA4(A31,x_,w3_) \
    x_ = sx4[2*20 + kq5 + kk2]; FMA4(A02,x_,w0_) FMA4(A12,x_,w1_) FMA4(A22,x_,w2_) FMA4(A32,x_,w3_) \
    x_ = sx4[3*20 + kq5 + kk2]; FMA4(A03,x_,w0_) FMA4(A13,x_,w1_) FMA4(A23,x_,w2_) FMA4(A33,x_,w3_) \
    x_ = sx4[4*20 + kq5 + kk2]; FMA4(A04,x_,w0_) FMA4(A14,x_,w1_) FMA4(A24,x_,w2_) FMA4(A34,x_,w3_) \
    x_ = sx4[5*20 + kq5 + kk2]; FMA4(A05,x_,w0_) FMA4(A15,x_,w1_) FMA4(A25,x_,w2_) FMA4(A35,x_,w3_) \
    x_ = sx4[6*20 + kq5 + kk2]; FMA4(A06,x_,w0_) FMA4(A16,x_,w1_) FMA4(A26,x_,w2_) FMA4(A36,x_,w3_) \
    x_ = sx4[7*20 + kq5 + kk2]; FMA4(A07,x_,w0_) FMA4(A17,x_,w1_) FMA4(A27,x_,w2_) FMA4(A37,x_,w3_) }

#define HG(kk) { \
    const int kk2 = ((kk) + s) & 7; \
    const int wb = kk2 * 512 + t; \
    float4 w0_ = whT[0*4096 + wb]; \
    float4 w1_ = whT[1*4096 + wb]; \
    float4 w2_ = whT[2*4096 + wb]; \
    float4 w3_ = whT[3*4096 + wb]; \
    float4 h_; \
    h_ = sh4[0*36 + kq9 + kk2]; FMA4(A00,h_,w0_) FMA4(A10,h_,w1_) FMA4(A20,h_,w2_) FMA4(A30,h_,w3_) \
    h_ = sh4[1*36 + kq9 + kk2]; FMA4(A01,h_,w0_) FMA4(A11,h_,w1_) FMA4(A21,h_,w2_) FMA4(A31,h_,w3_) \
    h_ = sh4[2*36 + kq9 + kk2]; FMA4(A02,h_,w0_) FMA4(A12,h_,w1_) FMA4(A22,h_,w2_) FMA4(A32,h_,w3_) \
    h_ = sh4[3*36 + kq9 + kk2]; FMA4(A03,h_,w0_) FMA4(A13,h_,w1_) FMA4(A23,h_,w2_) FMA4(A33,h_,w3_) \
    h_ = sh4[4*36 + kq9 + kk2]; FMA4(A04,h_,w0_) FMA4(A14,h_,w1_) FMA4(A24,h_,w2_) FMA4(A34,h_,w3_) \
    h_ = sh4[5*36 + kq9 + kk2]; FMA4(A05,h_,w0_) FMA4(A15,h_,w1_) FMA4(A25,h_,w2_) FMA4(A35,h_,w3_) \
    h_ = sh4[6*36 + kq9 + kk2]; FMA4(A06,h_,w0_) FMA4(A16,h_,w1_) FMA4(A26,h_,w2_) FMA4(A36,h_,w3_) \
    h_ = sh4[7*36 + kq9 + kk2]; FMA4(A07,h_,w0_) FMA4(A17,h_,w1_) FMA4(A27,h_,w2_) FMA4(A37,h_,w3_) }

#define RED2(A) A += __shfl_xor(A, 1); A += __shfl_xor(A, 2);
#define SELL(g) (kq == 0 ? A##g##0 : kq == 1 ? A##g##1 : kq == 2 ? A##g##2 : A##g##3)
#define SELH(g) (kq == 0 ? A##g##4 : kq == 1 ? A##g##5 : kq == 2 ? A##g##6 : A##g##7)

__global__ __launch_bounds__(512)
void lstm_out(
    const float*  __restrict__ ctx,   // [BS,SEQ,64]
    const float4* __restrict__ wiT,   // [(g*4+kk)*512 + t]
    const float4* __restrict__ whT,   // [(g*8+kk)*512 + t]
    const float*  __restrict__ b_ih, const float* __restrict__ b_hh,
    const float*  __restrict__ W_out, const float* __restrict__ b_out,
    float* __restrict__ out)          // [BS,64]
{
    const int t    = threadIdx.x;
    const int gq   = t >> 2;          // gate quad 0..127 -> gates 4gq..4gq+3
    const int kq   = t & 3;           // k-quarter
    const int kq5  = kq * 5;          // x quarter offset (float4s)
    const int kq9  = kq * 9;          // h quarter offset (float4s)
    const int row0 = blockIdx.x * 8;
    const int r2   = t >> 6;          // pointwise/staging row 0..7
    const int m    = t & 63;          // pointwise elem (m and m+64)

    // pointwise biases (gate order i,f,g,o = rows 0/128/256/384)
    const float bi0 = b_ih[m]       + b_hh[m];
    const float bf0 = b_ih[128 + m] + b_hh[128 + m];
    const float bg0 = b_ih[256 + m] + b_hh[256 + m];
    const float bo0 = b_ih[384 + m] + b_hh[384 + m];
    const float bi1 = b_ih[64 + m]  + b_hh[64 + m];
    const float bf1 = b_ih[192 + m] + b_hh[192 + m];
    const float bg1 = b_ih[320 + m] + b_hh[320 + m];
    const float bo1 = b_ih[448 + m] + b_hh[448 + m];

    __shared__ float s_x[8 * XROW];
    __shared__ float s_h[8 * HROWF];
    __shared__ float s_g[8 * SGS];

    const float4* sx4 = (const float4*)s_x;
    const float4* sh4 = (const float4*)s_h;

    const int xcol  = r2 * XROW + (m >> 4) * 20 + (m & 15);
    const int hcol0 = r2 * HROWF + (m >> 5) * 36 + (m & 31);
    const int hcol1 = r2 * HROWF + (2 + (m >> 5)) * 36 + (m & 31);

    float c0 = 0.f, c1 = 0.f;

    for (int s = 0; s < SEQ; ++s) {
        s_x[xcol] = ctx[((row0 + r2) * SEQ + s) * 64 + m];
        __syncthreads();

        float A00=0.f,A01=0.f,A02=0.f,A03=0.f,A04=0.f,A05=0.f,A06=0.f,A07=0.f;
        float A10=0.f,A11=0.f,A12=0.f,A13=0.f,A14=0.f,A15=0.f,A16=0.f,A17=0.f;
        float A20=0.f,A21=0.f,A22=0.f,A23=0.f,A24=0.f,A25=0.f,A26=0.f,A27=0.f;
        float A30=0.f,A31=0.f,A32=0.f,A33=0.f,A34=0.f,A35=0.f,A36=0.f,A37=0.f;

        XG(0) XG(1) XG(2) XG(3)
        if (s > 0) {
            HG(0) HG(1) HG(2) HG(3) HG(4) HG(5) HG(6) HG(7)
        }

        RED2(A00) RED2(A01) RED2(A02) RED2(A03) RED2(A04) RED2(A05) RED2(A06) RED2(A07)
        RED2(A10) RED2(A11) RED2(A12) RED2(A13) RED2(A14) RED2(A15) RED2(A16) RED2(A17)
        RED2(A20) RED2(A21) RED2(A22) RED2(A23) RED2(A24) RED2(A25) RED2(A26) RED2(A27)
        RED2(A30) RED2(A31) RED2(A32) RED2(A33) RED2(A34) RED2(A35) RED2(A36) RED2(A37)

        {   // lane kq writes rows kq and kq+4, gates 4gq..4gq+3 (b128 each)
            float4 glo = make_float4(SELL(0), SELL(1), SELL(2), SELL(3));
            float4 ghi = make_float4(SELH(0), SELH(1), SELH(2), SELH(3));
            *(float4*)&s_g[kq * SGS + (gq << 2)]       = glo;
            *(float4*)&s_g[(kq + 4) * SGS + (gq << 2)] = ghi;
        }
        __syncthreads();

        {   // pointwise for (r2, m) and (r2, m+64); c-state in registers
            const float* g0 = &s_g[r2 * SGS];
            float ig = sigf(g0[m] + bi0);
            float fg = sigf(g0[128 + m] + bf0);
            float gt = tanhfast(g0[256 + m] + bg0);
            float og = sigf(g0[384 + m] + bo0);
            c0 = fmaf(fg, c0, ig * gt);
            s_h[hcol0] = og * tanhfast(c0);

            float ih = sigf(g0[64 + m] + bi1);
            float fh = sigf(g0[192 + m] + bf1);
            float gh = tanhfast(g0[320 + m] + bg1);
            float oh = sigf(g0[448 + m] + bo1);
            c1 = fmaf(fh, c1, ih * gh);
            s_h[hcol1] = oh * tanhfast(c1);
        }
        __syncthreads();
    }

    // epilogue: out[row0+r2][m] = b_out[m] + h[r2] . W_out[m]
    {
        float acc = b_out[m];
        const float4* wp = (const float4*)&W_out[m * 128];
        #pragma unroll
        for (int q = 0; q < 4; ++q)
            #pragma unroll
            for (int i = 0; i < 8; ++i) {
                float4 h4 = sh4[r2 * 36 + q * 9 + i];   // broadcast read
                float4 w4 = wp[q * 8 + i];
                FMA4(acc, h4, w4)
            }
        out[(row0 + r2) * 64 + m] = acc;
    }
}

// ---------------------------------------------------------------------------
extern "C" void kernel_launch(void* const* d_in, const int* in_sizes, int n_in,
                              void* d_out, int out_size, void* d_ws, size_t ws_size,
                              hipStream_t stream) {
    (void)in_sizes; (void)n_in; (void)out_size; (void)ws_size;
    const float* seqs  = (const float*)d_in[0];
    const float* ets   = (const float*)d_in[1];
    const int*   masks = (const int*)d_in[2];
    const float* Wf  = (const float*)d_in[3];
    const float* bf  = (const float*)d_in[4];
    const float* Wk  = (const float*)d_in[5];
    const float* bk  = (const float*)d_in[6];
    const float* Wq  = (const float*)d_in[7];
    const float* bq  = (const float*)d_in[8];
    const float* Wv  = (const float*)d_in[9];
    const float* bv  = (const float*)d_in[10];
    const float* Wih = (const float*)d_in[11];
    const float* Whh = (const float*)d_in[12];
    const float* bih = (const float*)d_in[13];
    const float* bhh = (const float*)d_in[14];
    const float* Wo  = (const float*)d_in[15];
    const float* bo  = (const float*)d_in[16];

    // ws layout: wiT 128K | whT 256K | ctx 26.2M
    char* ws = (char*)d_ws;
    float4* wiT = (float4*)(ws);
    float4* whT = (float4*)(ws + 131072);
    float*  ctx = (float*) (ws + 131072 + 262144);

    hipLaunchKernelGGL(prep_w, dim3(48), dim3(512), 0, stream,
                       Wih, Whh, wiT, whT);
    hipLaunchKernelGGL(edge_attn_ctx, dim3(4096), dim3(64), 0, stream,
                       seqs, ets, masks, Wf, bf, Wk, bk, Wq, bq, Wv, bv, ctx);
    hipLaunchKernelGGL(lstm_out, dim3(256), dim3(512), 0, stream,
                       ctx, wiT, whT, bih, bhh, Wo, bo, (float*)d_out);
}